// Round 1
// baseline (389.408 us; speedup 1.0000x reference)
//
#include <hip/hip_runtime.h>
#include <math.h>

// NGP fused: 16-level 2D hash-grid encoding + bilerp + 3-layer MLP (32->32->32->3, sigmoid).
// 1 thread = 1 point. feats/h1/h2 fully register-resident (all loops unrolled).
// MLP weights are wave-uniform loads -> compiler emits s_load (scalar cache broadcast).

static constexpr int RL = 16;
static constexpr int TN = 65536;   // hash table entries per level

__global__ __launch_bounds__(256) void ngp_fused(
    const float2* __restrict__ x,
    const float2* __restrict__ hf,    // [16][65536] float2
    const float*  __restrict__ w1,    // [32][32]
    const float*  __restrict__ w2,    // [32][32]
    const float*  __restrict__ w3,    // [3][32]
    float* __restrict__ out,          // [M][3]
    int M)
{
    const int i = blockIdx.x * 256 + threadIdx.x;
    if (i >= M) return;
    const float2 c = x[i];

    // np.round(np.logspace(log2(16), log2(512), 16, base=2))
    constexpr int RES[16] = {16,20,25,32,40,51,64,81,102,128,161,203,256,323,406,512};

    float feats[32];
#pragma unroll
    for (int l = 0; l < RL; ++l) {
        const float rf = (float)RES[l];
        const float xs = c.x * rf;
        const float ys = c.y * rf;
        const float fx = floorf(xs);
        const float fy = floorf(ys);
        const int   xi = (int)fx;
        const int   yi = (int)fy;
        const float wx = xs - fx;
        const float wy = ys - fy;
        // hash = (xi ^ (A*yi)) & (N-1), A*yi wraps mod 2^32 (matches int32 semantics)
        const unsigned ay0 = 2654435761u * (unsigned)yi;
        const unsigned ay1 = 2654435761u * (unsigned)(yi + 1);
        const unsigned ux0 = (unsigned)xi;
        const unsigned ux1 = (unsigned)(xi + 1);
        const int h00 = (int)((ux0 ^ ay0) & (TN - 1));
        const int h01 = (int)((ux0 ^ ay1) & (TN - 1));
        const int h10 = (int)((ux1 ^ ay0) & (TN - 1));
        const int h11 = (int)((ux1 ^ ay1) & (TN - 1));
        const float2* __restrict__ t = hf + l * TN;
        const float2 f00 = t[h00];
        const float2 f01 = t[h01];
        const float2 f10 = t[h10];
        const float2 f11 = t[h11];
        const float w00 = (1.f - wx) * (1.f - wy);
        const float w01 = (1.f - wx) * wy;
        const float w10 = wx * (1.f - wy);
        const float w11 = wx * wy;
        const float scale = (float)(1u << l);   // 2^(l*SCALER), SCALER=1
        float f0 = f00.x * w00;
        f0 = fmaf(f01.x, w01, f0);
        f0 = fmaf(f10.x, w10, f0);
        f0 = fmaf(f11.x, w11, f0);
        float f1 = f00.y * w00;
        f1 = fmaf(f01.y, w01, f1);
        f1 = fmaf(f10.y, w10, f1);
        f1 = fmaf(f11.y, w11, f1);
        feats[2*l]     = f0 * scale;
        feats[2*l + 1] = f1 * scale;
    }

    // Layer 1: h1 = relu(feats @ w1.T)
    float h1[32];
#pragma unroll
    for (int j = 0; j < 32; ++j) {
        float acc = 0.f;
#pragma unroll
        for (int k = 0; k < 32; ++k) acc = fmaf(feats[k], w1[j*32 + k], acc);
        h1[j] = fmaxf(acc, 0.f);
    }

    // Layer 2: h2 = relu(h1 @ w2.T)
    float h2[32];
#pragma unroll
    for (int j = 0; j < 32; ++j) {
        float acc = 0.f;
#pragma unroll
        for (int k = 0; k < 32; ++k) acc = fmaf(h1[k], w2[j*32 + k], acc);
        h2[j] = fmaxf(acc, 0.f);
    }

    // Layer 3: out = sigmoid(h2 @ w3.T)
#pragma unroll
    for (int o = 0; o < 3; ++o) {
        float acc = 0.f;
#pragma unroll
        for (int k = 0; k < 32; ++k) acc = fmaf(h2[k], w3[o*32 + k], acc);
        out[3*i + o] = 1.f / (1.f + expf(-acc));
    }
}

extern "C" void kernel_launch(void* const* d_in, const int* in_sizes, int n_in,
                              void* d_out, int out_size, void* d_ws, size_t ws_size,
                              hipStream_t stream) {
    const float2* x  = (const float2*)d_in[0];
    const float2* hf = (const float2*)d_in[1];
    const float*  w1 = (const float*)d_in[2];
    const float*  w2 = (const float*)d_in[3];
    const float*  w3 = (const float*)d_in[4];
    float* out = (float*)d_out;
    const int M = in_sizes[0] / 2;
    const int grid = (M + 255) / 256;
    ngp_fused<<<grid, 256, 0, stream>>>(x, hf, w1, w2, w3, out, M);
}

// Round 5
// 370.540 us; speedup vs baseline: 1.0509x; 1.0509x over previous
//
#include <hip/hip_runtime.h>
#include <math.h>

// NGP fused, round 2 design (fourth submission — rounds 2-4 never acquired a GPU):
// dense pre-paired corner tables + batched paired gathers.
// Prepass: pair[l][y][x] = {hf[l][hash(x,y)], hf[l][hash(x+1,y)]} (float4, 16B aligned).
// Main kernel: per level, TWO aligned dwordx4 loads (row y0, row y0+1) replace
// four random 8B gathers. Levels processed in groups of 4 with all 8 loads
// issued before consumption (explicit latency-hiding pipeline). MLP still fp32 VALU.

static constexpr int RL = 16;
static constexpr int TN = 65536;

// np.round(np.logspace(log2(16), log2(512), 16, base=2))
static constexpr int RES[16]  = {16,20,25,32,40,51,64,81,102,128,161,203,256,323,406,512};
static constexpr int WD[16]   = {17,21,26,33,41,52,65,82,103,129,162,204,257,324,407,513};
// prefix sums of WD[l]^2 (pair-entry offsets)
static constexpr int OFFP[16] = {0,289,730,1406,2495,4176,6880,11105,17829,28438,
                                 45079,71323,112939,178988,283964,449613};
static constexpr int TOTP = 712782;           // total pair entries
static constexpr size_t WS_NEED = (size_t)TOTP * 16;  // 11.4 MB

__global__ __launch_bounds__(256) void build_pairs(
    const float2* __restrict__ hf,   // [16][65536]
    float4* __restrict__ dp)         // [TOTP] pre-paired dense grids
{
    const int l = blockIdx.y;
    const int W = WD[l];
    const int n = W * W;
    const int e = blockIdx.x * 256 + threadIdx.x;
    if (e >= n) return;
    const int y = e / W;
    const int x = e - y * W;
    const unsigned ay = 2654435761u * (unsigned)y;
    const unsigned h0 = ((unsigned)x       ^ ay) & 65535u;
    const unsigned h1 = ((unsigned)(x + 1) ^ ay) & 65535u;
    const float2* __restrict__ t = hf + l * TN;
    const float2 a = t[h0];
    const float2 b = t[h1];
    dp[OFFP[l] + e] = make_float4(a.x, a.y, b.x, b.y);
}

__global__ __launch_bounds__(256) void ngp_fused2(
    const float2* __restrict__ x,
    const float4* __restrict__ dp,
    const float*  __restrict__ w1,    // [32][32]
    const float*  __restrict__ w2,    // [32][32]
    const float*  __restrict__ w3,    // [3][32]
    float* __restrict__ out,          // [M][3]
    int M)
{
    const int i = blockIdx.x * 256 + threadIdx.x;
    if (i >= M) return;
    const float2 c = x[i];

    float feats[32];
#pragma unroll
    for (int g = 0; g < 4; ++g) {
        float4 r0[4], r1[4];
        float wxa[4], wya[4];
        // phase 1: addresses + issue all 8 paired loads for this group
#pragma unroll
        for (int t = 0; t < 4; ++t) {
            const int l = g * 4 + t;
            const float rf = (float)RES[l];
            const float xs = c.x * rf;
            const float ys = c.y * rf;
            const float fx = floorf(xs);
            const float fy = floorf(ys);
            const int x0 = (int)fx;
            const int y0 = (int)fy;
            wxa[t] = xs - fx;
            wya[t] = ys - fy;
            const int idx = OFFP[l] + y0 * WD[l] + x0;
            r0[t] = dp[idx];            // {f00, f10}
            r1[t] = dp[idx + WD[l]];    // {f01, f11}
        }
        // phase 2: bilerp
#pragma unroll
        for (int t = 0; t < 4; ++t) {
            const int l = g * 4 + t;
            const float wx = wxa[t];
            const float wy = wya[t];
            const float scale = (float)(1u << l);   // 2^(l*SCALER), SCALER=1
            const float e0 = fmaf(wx, r0[t].z - r0[t].x, r0[t].x);
            const float e1 = fmaf(wx, r0[t].w - r0[t].y, r0[t].y);
            const float o0 = fmaf(wx, r1[t].z - r1[t].x, r1[t].x);
            const float o1 = fmaf(wx, r1[t].w - r1[t].y, r1[t].y);
            feats[2*l]     = fmaf(wy, o0 - e0, e0) * scale;
            feats[2*l + 1] = fmaf(wy, o1 - e1, e1) * scale;
        }
    }

    // Layer 1: h1 = relu(feats @ w1.T)   (weights wave-uniform -> s_load broadcast)
    float h1[32];
#pragma unroll
    for (int j = 0; j < 32; ++j) {
        float acc = 0.f;
#pragma unroll
        for (int k = 0; k < 32; ++k) acc = fmaf(feats[k], w1[j*32 + k], acc);
        h1[j] = fmaxf(acc, 0.f);
    }

    // Layer 2
    float h2[32];
#pragma unroll
    for (int j = 0; j < 32; ++j) {
        float acc = 0.f;
#pragma unroll
        for (int k = 0; k < 32; ++k) acc = fmaf(h1[k], w2[j*32 + k], acc);
        h2[j] = fmaxf(acc, 0.f);
    }

    // Layer 3 + sigmoid
#pragma unroll
    for (int o = 0; o < 3; ++o) {
        float acc = 0.f;
#pragma unroll
        for (int k = 0; k < 32; ++k) acc = fmaf(h2[k], w3[o*32 + k], acc);
        out[3*i + o] = 1.f / (1.f + __expf(-acc));
    }
}

// ---- fallback (round-1 hashed path) if workspace is too small ----
__global__ __launch_bounds__(256) void ngp_fused_hashed(
    const float2* __restrict__ x,
    const float2* __restrict__ hf,
    const float*  __restrict__ w1,
    const float*  __restrict__ w2,
    const float*  __restrict__ w3,
    float* __restrict__ out,
    int M)
{
    const int i = blockIdx.x * 256 + threadIdx.x;
    if (i >= M) return;
    const float2 c = x[i];
    float feats[32];
#pragma unroll
    for (int l = 0; l < RL; ++l) {
        const float rf = (float)RES[l];
        const float xs = c.x * rf;
        const float ys = c.y * rf;
        const float fx = floorf(xs);
        const float fy = floorf(ys);
        const int xi = (int)fx;
        const int yi = (int)fy;
        const float wx = xs - fx;
        const float wy = ys - fy;
        const unsigned ay0 = 2654435761u * (unsigned)yi;
        const unsigned ay1 = 2654435761u * (unsigned)(yi + 1);
        const int h00 = (int)(((unsigned)xi ^ ay0) & 65535u);
        const int h01 = (int)(((unsigned)xi ^ ay1) & 65535u);
        const int h10 = (int)(((unsigned)(xi+1) ^ ay0) & 65535u);
        const int h11 = (int)(((unsigned)(xi+1) ^ ay1) & 65535u);
        const float2* __restrict__ t = hf + l * TN;
        const float2 f00 = t[h00], f01 = t[h01], f10 = t[h10], f11 = t[h11];
        const float e0 = fmaf(wx, f10.x - f00.x, f00.x);
        const float e1 = fmaf(wx, f10.y - f00.y, f00.y);
        const float o0 = fmaf(wx, f11.x - f01.x, f01.x);
        const float o1 = fmaf(wx, f11.y - f01.y, f01.y);
        const float scale = (float)(1u << l);
        feats[2*l]     = fmaf(wy, o0 - e0, e0) * scale;
        feats[2*l + 1] = fmaf(wy, o1 - e1, e1) * scale;
    }
    float h1[32];
#pragma unroll
    for (int j = 0; j < 32; ++j) {
        float acc = 0.f;
#pragma unroll
        for (int k = 0; k < 32; ++k) acc = fmaf(feats[k], w1[j*32 + k], acc);
        h1[j] = fmaxf(acc, 0.f);
    }
    float h2[32];
#pragma unroll
    for (int j = 0; j < 32; ++j) {
        float acc = 0.f;
#pragma unroll
        for (int k = 0; k < 32; ++k) acc = fmaf(h1[k], w2[j*32 + k], acc);
        h2[j] = fmaxf(acc, 0.f);
    }
#pragma unroll
    for (int o = 0; o < 3; ++o) {
        float acc = 0.f;
#pragma unroll
        for (int k = 0; k < 32; ++k) acc = fmaf(h2[k], w3[o*32 + k], acc);
        out[3*i + o] = 1.f / (1.f + __expf(-acc));
    }
}

extern "C" void kernel_launch(void* const* d_in, const int* in_sizes, int n_in,
                              void* d_out, int out_size, void* d_ws, size_t ws_size,
                              hipStream_t stream) {
    const float2* x  = (const float2*)d_in[0];
    const float2* hf = (const float2*)d_in[1];
    const float*  w1 = (const float*)d_in[2];
    const float*  w2 = (const float*)d_in[3];
    const float*  w3 = (const float*)d_in[4];
    float* out = (float*)d_out;
    const int M = in_sizes[0] / 2;
    const int grid = (M + 255) / 256;

    if (ws_size >= WS_NEED) {
        float4* dp = (float4*)d_ws;
        dim3 bgrid((263169 + 255) / 256, 16);   // largest level W^2 = 513^2
        build_pairs<<<bgrid, 256, 0, stream>>>(hf, dp);
        ngp_fused2<<<grid, 256, 0, stream>>>(x, dp, w1, w2, w3, out, M);
    } else {
        ngp_fused_hashed<<<grid, 256, 0, stream>>>(x, hf, w1, w2, w3, out, M);
    }
}

// Round 7
// 322.204 us; speedup vs baseline: 1.2086x; 1.1500x over previous
//
#include <hip/hip_runtime.h>
#include <math.h>

// NGP fused, round 6 design (resubmit — round 6 never acquired a GPU):
// hashed gathers (dense tables blew L2: FETCH 873MB in round 5) + f16 MFMA MLP.
// Per 64-pt wave: feats -> LDS [64][40 f16] (80B stride, 16B aligned),
// 20x mfma_f32_16x16x32_f16 for the 3 layers, wave-internal (no __syncthreads).
// Fragment layouts (CDNA 16x16x32): A: lane(r,g) holds A[r][8g..8g+7];
// B: lane(r,g) holds B[8g..8g+7][r]; D: lane(r,g) holds D[4g+q][r] (m89-verified).

typedef _Float16 f16x8 __attribute__((ext_vector_type(8)));
typedef float    f32x4 __attribute__((ext_vector_type(4)));

static constexpr int RESC[16] = {16,20,25,32,40,51,64,81,102,128,161,203,256,323,406,512};
static constexpr int STRB = 80;   // LDS row stride in bytes (32 f16 data + 8 f16 pad)

__device__ __forceinline__ float sigmoidf_(float a) { return 1.f / (1.f + __expf(-a)); }

__device__ __forceinline__ f16x8 load_wfrag(const float* __restrict__ w, int row, int g, bool valid) {
    f16x8 a;
    if (valid) {
        const float4 lo = *reinterpret_cast<const float4*>(w + row * 32 + g * 8);
        const float4 hi = *reinterpret_cast<const float4*>(w + row * 32 + g * 8 + 4);
        a[0]=(_Float16)lo.x; a[1]=(_Float16)lo.y; a[2]=(_Float16)lo.z; a[3]=(_Float16)lo.w;
        a[4]=(_Float16)hi.x; a[5]=(_Float16)hi.y; a[6]=(_Float16)hi.z; a[7]=(_Float16)hi.w;
    } else {
#pragma unroll
        for (int j = 0; j < 8; ++j) a[j] = (_Float16)0.f;
    }
    return a;
}

__global__ __launch_bounds__(256) void ngp_mfma(
    const float2* __restrict__ x,
    const float2* __restrict__ hf,    // [16][65536]
    const float*  __restrict__ w1,    // [32][32]
    const float*  __restrict__ w2,    // [32][32]
    const float*  __restrict__ w3,    // [3][32]
    float* __restrict__ out)          // [M][3]
{
    __shared__ char smem[4][64 * STRB];   // 20 KB: one feats/h buffer per wave
    const int tid  = threadIdx.x;
    const int wv   = tid >> 6;
    const int lane = tid & 63;
    const int r    = lane & 15;
    const int g    = lane >> 4;
    char* sb = smem[wv];

    const int i = blockIdx.x * 256 + tid;
    const float2 c = x[i];

    // ---- encoding: hashed gathers, pack f16 feat-pairs into LDS row `lane`
    unsigned* srow = reinterpret_cast<unsigned*>(sb + lane * STRB);
#pragma unroll
    for (int l = 0; l < 16; ++l) {
        const float rf = (float)RESC[l];
        const float xs = c.x * rf, ys = c.y * rf;
        const float fx = floorf(xs), fy = floorf(ys);
        const int   xi = (int)fx,  yi = (int)fy;
        const float wx = xs - fx,  wy = ys - fy;
        const unsigned ay0 = 2654435761u * (unsigned)yi;
        const unsigned ay1 = 2654435761u * (unsigned)(yi + 1);
        const int h00 = (int)(((unsigned)xi       ^ ay0) & 65535u);
        const int h01 = (int)(((unsigned)xi       ^ ay1) & 65535u);
        const int h10 = (int)(((unsigned)(xi + 1) ^ ay0) & 65535u);
        const int h11 = (int)(((unsigned)(xi + 1) ^ ay1) & 65535u);
        const float2* t = hf + l * 65536;
        const float2 f00 = t[h00], f01 = t[h01], f10 = t[h10], f11 = t[h11];
        const float e0 = fmaf(wx, f10.x - f00.x, f00.x);
        const float e1 = fmaf(wx, f10.y - f00.y, f00.y);
        const float o0 = fmaf(wx, f11.x - f01.x, f01.x);
        const float o1 = fmaf(wx, f11.y - f01.y, f01.y);
        const float sc = (float)(1u << l);     // 2^(l*SCALER), SCALER=1
        const float f0 = fmaf(wy, o0 - e0, e0) * sc;
        const float f1 = fmaf(wy, o1 - e1, e1) * sc;
        union { _Float16 h[2]; unsigned u; } pk;
        pk.h[0] = (_Float16)f0; pk.h[1] = (_Float16)f1;
        srow[l] = pk.u;                        // bytes [4l, 4l+4) of this point's row
    }

    // ---- weight A-fragments (row = output neuron within tile, k-block = g)
    f16x8 a1[2], a2[2], a3;
    a1[0] = load_wfrag(w1, r,      g, true);
    a1[1] = load_wfrag(w1, 16 + r, g, true);
    a2[0] = load_wfrag(w2, r,      g, true);
    a2[1] = load_wfrag(w2, 16 + r, g, true);
    a3    = load_wfrag(w3, r,      g, r < 3);  // rows 3..15 zero-padded

    const f32x4 zero = {0.f, 0.f, 0.f, 0.f};
    f16x8 bfr[4];

    // ---- layer 1: h1 = relu(w1 @ featsT)  [32 x 64], written back transposed
#pragma unroll
    for (int pt = 0; pt < 4; ++pt)
        bfr[pt] = *reinterpret_cast<const f16x8*>(sb + (pt * 16 + r) * STRB + g * 16);
#pragma unroll
    for (int nt = 0; nt < 2; ++nt) {
#pragma unroll
        for (int pt = 0; pt < 4; ++pt) {
            f32x4 acc = __builtin_amdgcn_mfma_f32_16x16x32_f16(a1[nt], bfr[pt], zero, 0, 0, 0);
            union { _Float16 h[4]; uint2 u; } pk;
#pragma unroll
            for (int q = 0; q < 4; ++q) pk.h[q] = (_Float16)fmaxf(acc[q], 0.f);
            // point = pt*16 + r (D col), neurons nt*16 + 4g .. +3 (D rows)
            *reinterpret_cast<uint2*>(sb + (pt * 16 + r) * STRB + nt * 32 + g * 8) = pk.u;
        }
    }

    // ---- layer 2: h2 = relu(w2 @ h1T)
#pragma unroll
    for (int pt = 0; pt < 4; ++pt)
        bfr[pt] = *reinterpret_cast<const f16x8*>(sb + (pt * 16 + r) * STRB + g * 16);
#pragma unroll
    for (int nt = 0; nt < 2; ++nt) {
#pragma unroll
        for (int pt = 0; pt < 4; ++pt) {
            f32x4 acc = __builtin_amdgcn_mfma_f32_16x16x32_f16(a2[nt], bfr[pt], zero, 0, 0, 0);
            union { _Float16 h[4]; uint2 u; } pk;
#pragma unroll
            for (int q = 0; q < 4; ++q) pk.h[q] = (_Float16)fmaxf(acc[q], 0.f);
            *reinterpret_cast<uint2*>(sb + (pt * 16 + r) * STRB + nt * 32 + g * 8) = pk.u;
        }
    }

    // ---- layer 3: out = sigmoid(w3 @ h2T), rows 0..2 live in lanes g==0
#pragma unroll
    for (int pt = 0; pt < 4; ++pt)
        bfr[pt] = *reinterpret_cast<const f16x8*>(sb + (pt * 16 + r) * STRB + g * 16);
#pragma unroll
    for (int pt = 0; pt < 4; ++pt) {
        f32x4 acc = __builtin_amdgcn_mfma_f32_16x16x32_f16(a3, bfr[pt], zero, 0, 0, 0);
        if (g == 0) {
            const int p = blockIdx.x * 256 + wv * 64 + pt * 16 + r;
            out[p * 3 + 0] = sigmoidf_(acc[0]);
            out[p * 3 + 1] = sigmoidf_(acc[1]);
            out[p * 3 + 2] = sigmoidf_(acc[2]);
        }
    }
}

// ---- scalar tail kernel for points [base, M) when M % 256 != 0 (not hit at M=2^21)
__global__ __launch_bounds__(256) void ngp_tail(
    const float2* __restrict__ x, const float2* __restrict__ hf,
    const float* __restrict__ w1, const float* __restrict__ w2,
    const float* __restrict__ w3, float* __restrict__ out, int base, int M)
{
    const int i = base + blockIdx.x * 256 + threadIdx.x;
    if (i >= M) return;
    const float2 c = x[i];
    float feats[32];
#pragma unroll
    for (int l = 0; l < 16; ++l) {
        const float rf = (float)RESC[l];
        const float xs = c.x * rf, ys = c.y * rf;
        const float fx = floorf(xs), fy = floorf(ys);
        const int xi = (int)fx, yi = (int)fy;
        const float wx = xs - fx, wy = ys - fy;
        const unsigned ay0 = 2654435761u * (unsigned)yi;
        const unsigned ay1 = 2654435761u * (unsigned)(yi + 1);
        const int h00 = (int)(((unsigned)xi     ^ ay0) & 65535u);
        const int h01 = (int)(((unsigned)xi     ^ ay1) & 65535u);
        const int h10 = (int)(((unsigned)(xi+1) ^ ay0) & 65535u);
        const int h11 = (int)(((unsigned)(xi+1) ^ ay1) & 65535u);
        const float2* t = hf + l * 65536;
        const float2 f00 = t[h00], f01 = t[h01], f10 = t[h10], f11 = t[h11];
        const float e0 = fmaf(wx, f10.x - f00.x, f00.x);
        const float e1 = fmaf(wx, f10.y - f00.y, f00.y);
        const float o0 = fmaf(wx, f11.x - f01.x, f01.x);
        const float o1 = fmaf(wx, f11.y - f01.y, f01.y);
        const float sc = (float)(1u << l);
        feats[2*l]   = fmaf(wy, o0 - e0, e0) * sc;
        feats[2*l+1] = fmaf(wy, o1 - e1, e1) * sc;
    }
    float h1[32];
#pragma unroll
    for (int j = 0; j < 32; ++j) {
        float acc = 0.f;
#pragma unroll
        for (int k = 0; k < 32; ++k) acc = fmaf(feats[k], w1[j*32+k], acc);
        h1[j] = fmaxf(acc, 0.f);
    }
    float h2[32];
#pragma unroll
    for (int j = 0; j < 32; ++j) {
        float acc = 0.f;
#pragma unroll
        for (int k = 0; k < 32; ++k) acc = fmaf(h1[k], w2[j*32+k], acc);
        h2[j] = fmaxf(acc, 0.f);
    }
#pragma unroll
    for (int o = 0; o < 3; ++o) {
        float acc = 0.f;
#pragma unroll
        for (int k = 0; k < 32; ++k) acc = fmaf(h2[k], w3[o*32+k], acc);
        out[3*i + o] = 1.f / (1.f + __expf(-acc));
    }
}

extern "C" void kernel_launch(void* const* d_in, const int* in_sizes, int n_in,
                              void* d_out, int out_size, void* d_ws, size_t ws_size,
                              hipStream_t stream) {
    const float2* x  = (const float2*)d_in[0];
    const float2* hf = (const float2*)d_in[1];
    const float*  w1 = (const float*)d_in[2];
    const float*  w2 = (const float*)d_in[3];
    const float*  w3 = (const float*)d_in[4];
    float* out = (float*)d_out;
    const int M = in_sizes[0] / 2;

    const int full = M / 256;               // full 256-pt blocks (M=2^21 -> 8192)
    if (full > 0)
        ngp_mfma<<<full, 256, 0, stream>>>(x, hf, w1, w2, w3, out);
    const int base = full * 256;
    const int rem  = M - base;
    if (rem > 0)
        ngp_tail<<<(rem + 255) / 256, 256, 0, stream>>>(x, hf, w1, w2, w3, out, base, M);
}

// Round 11
// 248.234 us; speedup vs baseline: 1.5687x; 1.2980x over previous
//
#include <hip/hip_runtime.h>
#include <math.h>

// NGP fused, round 8 design (fourth submission — rounds 8-10 never acquired a GPU):
// quad-packed dense f16 tables for levels 0-11 (1 gather/level),
// f16-packed hashed tables for levels 12-15 (4B entries), f16 MFMA MLP (round-6, verified).
// Gather requests/point: 64 -> 28. Hot set ~2.8MB (L2-resident; round-5 lesson: never
// densify high-res levels). Prepass rebuilds workspace every call (re-poison safe).

typedef _Float16 f16x8 __attribute__((ext_vector_type(8)));
typedef float    f32x4 __attribute__((ext_vector_type(4)));

static constexpr int RESC[16] = {16,20,25,32,40,51,64,81,102,128,161,203,256,323,406,512};
// prefix sums of res^2 for levels 0..11 (quad-table entry offsets, 16B units)
static constexpr int QOFF[12] = {0,256,656,1281,2305,3905,6506,10602,17163,27567,43951,69872};
static constexpr int QTOT = 111081;                       // total quad cells
static constexpr size_t QBYTES = (size_t)QTOT * 16;       // 1,777,296 B (16B-aligned)
static constexpr size_t WS_NEED = QBYTES + 4u * 65536u * 4u;  // + 1MB f16 hash tables
static constexpr int STRB = 80;   // LDS row stride (32 f16 data + 8 f16 pad; 2-way bank alias = free)

__device__ __forceinline__ float sigmoidf_(float a) { return 1.f / (1.f + __expf(-a)); }

// ---- prepass: build quad tables (levels 0-11) + f16-pack hashed tables (12-15)
__global__ __launch_bounds__(256) void build_tabs(
    const float2* __restrict__ hf,   // [16][65536]
    uint4* __restrict__ quad,        // [QTOT] {f00,f10,f01,f11} as f16x8
    unsigned* __restrict__ h16)      // [4][65536] f16x2
{
    const int l = blockIdx.y;
    const int e = blockIdx.x * 256 + threadIdx.x;
    if (l < 12) {
        const int res = RESC[l];
        const int n = res * res;
        if (e >= n) return;
        const int y = e / res;
        const int x = e - y * res;
        const unsigned ay0 = 2654435761u * (unsigned)y;
        const unsigned ay1 = 2654435761u * (unsigned)(y + 1);
        const int h00 = (int)(((unsigned)x       ^ ay0) & 65535u);
        const int h10 = (int)(((unsigned)(x + 1) ^ ay0) & 65535u);
        const int h01 = (int)(((unsigned)x       ^ ay1) & 65535u);
        const int h11 = (int)(((unsigned)(x + 1) ^ ay1) & 65535u);
        const float2* t = hf + l * 65536;
        const float2 f00 = t[h00], f10 = t[h10], f01 = t[h01], f11 = t[h11];
        union { _Float16 h[8]; uint4 u; } pk;
        pk.h[0] = (_Float16)f00.x; pk.h[1] = (_Float16)f00.y;
        pk.h[2] = (_Float16)f10.x; pk.h[3] = (_Float16)f10.y;
        pk.h[4] = (_Float16)f01.x; pk.h[5] = (_Float16)f01.y;
        pk.h[6] = (_Float16)f11.x; pk.h[7] = (_Float16)f11.y;
        quad[QOFF[l] + e] = pk.u;
    } else {
        if (e >= 65536) return;
        const float2 v = hf[l * 65536 + e];
        union { _Float16 h[2]; unsigned u; } pk;
        pk.h[0] = (_Float16)v.x; pk.h[1] = (_Float16)v.y;
        h16[(l - 12) * 65536 + e] = pk.u;
    }
}

__device__ __forceinline__ f16x8 load_wfrag(const float* __restrict__ w, int row, int g, bool valid) {
    f16x8 a;
    if (valid) {
        const float4 lo = *reinterpret_cast<const float4*>(w + row * 32 + g * 8);
        const float4 hi = *reinterpret_cast<const float4*>(w + row * 32 + g * 8 + 4);
        a[0]=(_Float16)lo.x; a[1]=(_Float16)lo.y; a[2]=(_Float16)lo.z; a[3]=(_Float16)lo.w;
        a[4]=(_Float16)hi.x; a[5]=(_Float16)hi.y; a[6]=(_Float16)hi.z; a[7]=(_Float16)hi.w;
    } else {
#pragma unroll
        for (int j = 0; j < 8; ++j) a[j] = (_Float16)0.f;
    }
    return a;
}

__global__ __launch_bounds__(256) void ngp_mfma2(
    const float2* __restrict__ x,
    const uint4*  __restrict__ quad,
    const unsigned* __restrict__ h16,
    const float*  __restrict__ w1,
    const float*  __restrict__ w2,
    const float*  __restrict__ w3,
    float* __restrict__ out)
{
    __shared__ char smem[4][64 * STRB];
    const int tid  = threadIdx.x;
    const int wv   = tid >> 6;
    const int lane = tid & 63;
    const int r    = lane & 15;
    const int g    = lane >> 4;
    char* sb = smem[wv];

    const int i = blockIdx.x * 256 + tid;
    const float2 c = x[i];

    // ---- phase 1: all 28 gather requests issued before consumption
    uint4 q[12];
    float wxa[16], wya[16];
#pragma unroll
    for (int l = 0; l < 12; ++l) {
        const float rf = (float)RESC[l];
        const float xs = c.x * rf, ys = c.y * rf;
        const float fx = floorf(xs), fy = floorf(ys);
        wxa[l] = xs - fx; wya[l] = ys - fy;
        const int x0 = (int)fx, y0 = (int)fy;
        q[l] = quad[QOFF[l] + y0 * RESC[l] + x0];
    }
    unsigned u00[4], u01[4], u10[4], u11[4];
#pragma unroll
    for (int t = 0; t < 4; ++t) {
        const int l = 12 + t;
        const float rf = (float)RESC[l];
        const float xs = c.x * rf, ys = c.y * rf;
        const float fx = floorf(xs), fy = floorf(ys);
        wxa[l] = xs - fx; wya[l] = ys - fy;
        const int xi = (int)fx, yi = (int)fy;
        const unsigned ay0 = 2654435761u * (unsigned)yi;
        const unsigned ay1 = 2654435761u * (unsigned)(yi + 1);
        const unsigned* tb = h16 + t * 65536;
        u00[t] = tb[((unsigned)xi       ^ ay0) & 65535u];
        u01[t] = tb[((unsigned)xi       ^ ay1) & 65535u];
        u10[t] = tb[((unsigned)(xi + 1) ^ ay0) & 65535u];
        u11[t] = tb[((unsigned)(xi + 1) ^ ay1) & 65535u];
    }

    // ---- phase 2: bilerp, pack f16 feat-pairs into LDS row `lane`
    unsigned* srow = reinterpret_cast<unsigned*>(sb + lane * STRB);
#pragma unroll
    for (int l = 0; l < 12; ++l) {
        union { uint4 u; _Float16 h[8]; } pk; pk.u = q[l];
        const float wx = wxa[l], wy = wya[l];
        const float e0 = fmaf(wx, (float)pk.h[2] - (float)pk.h[0], (float)pk.h[0]);
        const float e1 = fmaf(wx, (float)pk.h[3] - (float)pk.h[1], (float)pk.h[1]);
        const float o0 = fmaf(wx, (float)pk.h[6] - (float)pk.h[4], (float)pk.h[4]);
        const float o1 = fmaf(wx, (float)pk.h[7] - (float)pk.h[5], (float)pk.h[5]);
        const float sc = (float)(1u << l);
        union { _Float16 h[2]; unsigned u; } o;
        o.h[0] = (_Float16)(fmaf(wy, o0 - e0, e0) * sc);
        o.h[1] = (_Float16)(fmaf(wy, o1 - e1, e1) * sc);
        srow[l] = o.u;
    }
#pragma unroll
    for (int t = 0; t < 4; ++t) {
        const int l = 12 + t;
        union { unsigned u; _Float16 h[2]; } a, b, cc, d;
        a.u = u00[t]; b.u = u10[t]; cc.u = u01[t]; d.u = u11[t];
        const float wx = wxa[l], wy = wya[l];
        const float e0 = fmaf(wx, (float)b.h[0] - (float)a.h[0], (float)a.h[0]);
        const float e1 = fmaf(wx, (float)b.h[1] - (float)a.h[1], (float)a.h[1]);
        const float o0 = fmaf(wx, (float)d.h[0] - (float)cc.h[0], (float)cc.h[0]);
        const float o1 = fmaf(wx, (float)d.h[1] - (float)cc.h[1], (float)cc.h[1]);
        const float sc = (float)(1u << l);
        union { _Float16 h[2]; unsigned u; } o;
        o.h[0] = (_Float16)(fmaf(wy, o0 - e0, e0) * sc);
        o.h[1] = (_Float16)(fmaf(wy, o1 - e1, e1) * sc);
        srow[l] = o.u;
    }

    // ---- MFMA MLP (round-6 structure, verified): wave-internal, no barriers
    f16x8 a1[2], a2[2], a3;
    a1[0] = load_wfrag(w1, r,      g, true);
    a1[1] = load_wfrag(w1, 16 + r, g, true);
    a2[0] = load_wfrag(w2, r,      g, true);
    a2[1] = load_wfrag(w2, 16 + r, g, true);
    a3    = load_wfrag(w3, r,      g, r < 3);

    const f32x4 zero = {0.f, 0.f, 0.f, 0.f};
    f16x8 bfr[4];

#pragma unroll
    for (int pt = 0; pt < 4; ++pt)
        bfr[pt] = *reinterpret_cast<const f16x8*>(sb + (pt * 16 + r) * STRB + g * 16);
#pragma unroll
    for (int nt = 0; nt < 2; ++nt) {
#pragma unroll
        for (int pt = 0; pt < 4; ++pt) {
            f32x4 acc = __builtin_amdgcn_mfma_f32_16x16x32_f16(a1[nt], bfr[pt], zero, 0, 0, 0);
            union { _Float16 h[4]; uint2 u; } pk;
#pragma unroll
            for (int qq = 0; qq < 4; ++qq) pk.h[qq] = (_Float16)fmaxf(acc[qq], 0.f);
            *reinterpret_cast<uint2*>(sb + (pt * 16 + r) * STRB + nt * 32 + g * 8) = pk.u;
        }
    }
#pragma unroll
    for (int pt = 0; pt < 4; ++pt)
        bfr[pt] = *reinterpret_cast<const f16x8*>(sb + (pt * 16 + r) * STRB + g * 16);
#pragma unroll
    for (int nt = 0; nt < 2; ++nt) {
#pragma unroll
        for (int pt = 0; pt < 4; ++pt) {
            f32x4 acc = __builtin_amdgcn_mfma_f32_16x16x32_f16(a2[nt], bfr[pt], zero, 0, 0, 0);
            union { _Float16 h[4]; uint2 u; } pk;
#pragma unroll
            for (int qq = 0; qq < 4; ++qq) pk.h[qq] = (_Float16)fmaxf(acc[qq], 0.f);
            *reinterpret_cast<uint2*>(sb + (pt * 16 + r) * STRB + nt * 32 + g * 8) = pk.u;
        }
    }
#pragma unroll
    for (int pt = 0; pt < 4; ++pt)
        bfr[pt] = *reinterpret_cast<const f16x8*>(sb + (pt * 16 + r) * STRB + g * 16);
#pragma unroll
    for (int pt = 0; pt < 4; ++pt) {
        f32x4 acc = __builtin_amdgcn_mfma_f32_16x16x32_f16(a3, bfr[pt], zero, 0, 0, 0);
        if (g == 0) {
            const int p = blockIdx.x * 256 + wv * 64 + pt * 16 + r;
            out[p * 3 + 0] = sigmoidf_(acc[0]);
            out[p * 3 + 1] = sigmoidf_(acc[1]);
            out[p * 3 + 2] = sigmoidf_(acc[2]);
        }
    }
}

// ---- scalar tail / fallback (round-1 hashed, fp32) ----
__global__ __launch_bounds__(256) void ngp_tail(
    const float2* __restrict__ x, const float2* __restrict__ hf,
    const float* __restrict__ w1, const float* __restrict__ w2,
    const float* __restrict__ w3, float* __restrict__ out, int base, int M)
{
    const int i = base + blockIdx.x * 256 + threadIdx.x;
    if (i >= M) return;
    const float2 c = x[i];
    float feats[32];
#pragma unroll
    for (int l = 0; l < 16; ++l) {
        const float rf = (float)RESC[l];
        const float xs = c.x * rf, ys = c.y * rf;
        const float fx = floorf(xs), fy = floorf(ys);
        const int xi = (int)fx, yi = (int)fy;
        const float wx = xs - fx, wy = ys - fy;
        const unsigned ay0 = 2654435761u * (unsigned)yi;
        const unsigned ay1 = 2654435761u * (unsigned)(yi + 1);
        const int h00 = (int)(((unsigned)xi     ^ ay0) & 65535u);
        const int h01 = (int)(((unsigned)xi     ^ ay1) & 65535u);
        const int h10 = (int)(((unsigned)(xi+1) ^ ay0) & 65535u);
        const int h11 = (int)(((unsigned)(xi+1) ^ ay1) & 65535u);
        const float2* t = hf + l * 65536;
        const float2 f00 = t[h00], f01 = t[h01], f10 = t[h10], f11 = t[h11];
        const float e0 = fmaf(wx, f10.x - f00.x, f00.x);
        const float e1 = fmaf(wx, f10.y - f00.y, f00.y);
        const float o0 = fmaf(wx, f11.x - f01.x, f01.x);
        const float o1 = fmaf(wx, f11.y - f01.y, f01.y);
        const float sc = (float)(1u << l);
        feats[2*l]   = fmaf(wy, o0 - e0, e0) * sc;
        feats[2*l+1] = fmaf(wy, o1 - e1, e1) * sc;
    }
    float h1[32];
#pragma unroll
    for (int j = 0; j < 32; ++j) {
        float acc = 0.f;
#pragma unroll
        for (int k = 0; k < 32; ++k) acc = fmaf(feats[k], w1[j*32+k], acc);
        h1[j] = fmaxf(acc, 0.f);
    }
    float h2[32];
#pragma unroll
    for (int j = 0; j < 32; ++j) {
        float acc = 0.f;
#pragma unroll
        for (int k = 0; k < 32; ++k) acc = fmaf(h1[k], w2[j*32+k], acc);
        h2[j] = fmaxf(acc, 0.f);
    }
#pragma unroll
    for (int o = 0; o < 3; ++o) {
        float acc = 0.f;
#pragma unroll
        for (int k = 0; k < 32; ++k) acc = fmaf(h2[k], w3[o*32+k], acc);
        out[3*i + o] = 1.f / (1.f + __expf(-acc));
    }
}

extern "C" void kernel_launch(void* const* d_in, const int* in_sizes, int n_in,
                              void* d_out, int out_size, void* d_ws, size_t ws_size,
                              hipStream_t stream) {
    const float2* x  = (const float2*)d_in[0];
    const float2* hf = (const float2*)d_in[1];
    const float*  w1 = (const float*)d_in[2];
    const float*  w2 = (const float*)d_in[3];
    const float*  w3 = (const float*)d_in[4];
    float* out = (float*)d_out;
    const int M = in_sizes[0] / 2;

    if (ws_size >= WS_NEED) {
        uint4*    quad = (uint4*)d_ws;
        unsigned* h16  = (unsigned*)((char*)d_ws + QBYTES);
        build_tabs<<<dim3(256, 16), 256, 0, stream>>>(hf, quad, h16);
        const int full = M / 256;
        if (full > 0)
            ngp_mfma2<<<full, 256, 0, stream>>>(x, quad, h16, w1, w2, w3, out);
        const int base = full * 256;
        if (M - base > 0)
            ngp_tail<<<((M - base) + 255) / 256, 256, 0, stream>>>(x, hf, w1, w2, w3, out, base, M);
    } else {
        ngp_tail<<<(M + 255) / 256, 256, 0, stream>>>(x, hf, w1, w2, w3, out, 0, M);
    }
}